// Round 3
// baseline (235.250 us; speedup 1.0000x reference)
//
#include <hip/hip_runtime.h>
#include <stdint.h>

#define N_PTS 65536
#define NBINS 32768      // positive f32 -> bits>>16 in [0, 32768)
#define CAND_CAP 4096
typedef unsigned long long u64;

// ws layout
//   [0    , 256K)  scores  f32[65536]
//   [256K , 384K)  hist    u32[32768]

// ---------------------------------------------------------------------------
// K1: per-point MLP score (batch 0 only) + histogram of score high-16 bits.
// Weights read DIRECTLY from global with wave-uniform indices -> scalar loads
// (s_load) on the scalar pipe; no LDS, no __syncthreads, small I$ footprint.
// ---------------------------------------------------------------------------
__global__ __launch_bounds__(256, 1) void score_kernel(
    const float* __restrict__ src,
    const float* __restrict__ W1, const float* __restrict__ b1,
    const float* __restrict__ W2, const float* __restrict__ b2,
    const float* __restrict__ Wa, const float* __restrict__ ba,
    const float* __restrict__ Wb, const float* __restrict__ bb,
    const float* __restrict__ Wc, const float* __restrict__ bc,
    float* __restrict__ scores, unsigned* __restrict__ hist)
{
    const int n = blockIdx.x * 256 + threadIdx.x;

    float x[6];
    #pragma unroll
    for (int c = 0; c < 6; c++) x[c] = src[c * N_PTS + n];   // batch 0

    // layer 1: 6 -> 32
    float h1[32];
    #pragma unroll
    for (int j = 0; j < 32; j++) {
        float s = b1[j];
        #pragma unroll
        for (int c = 0; c < 6; c++) s = fmaf(W1[j * 6 + c], x[c], s);
        h1[j] = fmaxf(s, 0.f);
    }

    // layers 2+3 fused: 32 -> 64 -> 16, neuron-blocked by 8, rolled loop
    float h3[16];
    #pragma unroll
    for (int q = 0; q < 16; q++) h3[q] = ba[q];

    #pragma unroll 1
    for (int jb = 0; jb < 64; jb += 8) {
        float v[8];
        #pragma unroll
        for (int u = 0; u < 8; u++) {
            const int j = jb + u;
            float s0 = 0.f, s1 = 0.f, s2 = 0.f, s3 = 0.f;
            #pragma unroll
            for (int i = 0; i < 32; i += 4) {
                s0 = fmaf(W2[j * 32 + i + 0], h1[i + 0], s0);
                s1 = fmaf(W2[j * 32 + i + 1], h1[i + 1], s1);
                s2 = fmaf(W2[j * 32 + i + 2], h1[i + 2], s2);
                s3 = fmaf(W2[j * 32 + i + 3], h1[i + 3], s3);
            }
            v[u] = fmaxf(((s0 + s1) + (s2 + s3)) + b2[j], 0.f);
        }
        #pragma unroll
        for (int q = 0; q < 16; q++) {
            float a = h3[q];
            #pragma unroll
            for (int u = 0; u < 8; u++) a = fmaf(Wa[q * 64 + jb + u], v[u], a);
            h3[q] = a;
        }
    }
    #pragma unroll
    for (int q = 0; q < 16; q++) h3[q] = fmaxf(h3[q], 0.f);

    // layers 4+5: 16 -> 8 -> 1
    float z = bc[0];
    #pragma unroll
    for (int j = 0; j < 8; j++) {
        float s0 = bb[j], s1 = 0.f;
        #pragma unroll
        for (int q = 0; q < 16; q += 2) {
            s0 = fmaf(Wb[j * 16 + q + 0], h3[q + 0], s0);
            s1 = fmaf(Wb[j * 16 + q + 1], h3[q + 1], s1);
        }
        z = fmaf(Wc[j], fmaxf(s0 + s1, 0.f), z);
    }

    const float sp = fmaxf(z, 0.f) + log1pf(expf(-fabsf(z)));
    scores[n] = sp;
    atomicAdd(&hist[__float_as_uint(sp) >> 16], 1u);
}

// ---------------------------------------------------------------------------
// K2: fused select. One block, 1024 threads.
//   (a) suffix-scan histogram -> threshold bin T (all true top-64 have bin>=T)
//   (b) compact candidates with bin >= T into LDS (composite key)
//   (c) bitonic-sort next_pow2(count) keys desc -> exact lax.top_k order
//   (d) gather out[b,k,c] = src[b,c,idx[k]]
// Key = (score_bits << 32) | ~idx  -> value desc, lower idx first on ties.
// ---------------------------------------------------------------------------
__global__ __launch_bounds__(1024) void select_kernel(
    const unsigned* __restrict__ hist, const float* __restrict__ scores,
    const float* __restrict__ src, float* __restrict__ out)
{
    __shared__ unsigned chunk[1024];
    __shared__ u64 keys[CAND_CAP];
    __shared__ int idxs[64];
    __shared__ int sh_T, sh_count;
    const int t = threadIdx.x;

    // (a) per-thread sum of 32 bins
    {
        unsigned s = 0;
        const uint4* h4 = (const uint4*)(hist + t * 32);
        #pragma unroll
        for (int i = 0; i < 8; i++) {
            uint4 v = h4[i];
            s += v.x + v.y + v.z + v.w;
        }
        chunk[t] = s;
    }
    __syncthreads();
    // suffix scan over 1024 chunks
    for (int d = 1; d < 1024; d <<= 1) {
        unsigned v = (t + d < 1024) ? chunk[t + d] : 0u;
        __syncthreads();
        chunk[t] += v;
        __syncthreads();
    }
    if (t == 0) sh_count = 0;
    {
        const unsigned here = chunk[t];
        const unsigned nxt = (t + 1 < 1024) ? chunk[t + 1] : 0u;
        if (here >= 64u && nxt < 64u) {
            // refine within bins [t*32, t*32+32): walk top-down
            unsigned c = nxt;
            int T = t * 32;
            for (int b = t * 32 + 31; b >= t * 32; b--) {
                c += hist[b];
                if (c >= 64u) { T = b; break; }
            }
            sh_T = T;
        }
    }
    __syncthreads();
    const int T = sh_T;

    // (b) compact: scan all 65536 scores (vectorized), append bin>=T to LDS
    {
        const float4* s4 = (const float4*)scores;
        for (int i = t; i < N_PTS / 4; i += 1024) {
            float4 v = s4[i];
            const int n0 = 4 * i;
            unsigned b;
            b = __float_as_uint(v.x);
            if ((int)(b >> 16) >= T) { int p = atomicAdd(&sh_count, 1); if (p < CAND_CAP) keys[p] = ((u64)b << 32) | (unsigned)~(n0 + 0); }
            b = __float_as_uint(v.y);
            if ((int)(b >> 16) >= T) { int p = atomicAdd(&sh_count, 1); if (p < CAND_CAP) keys[p] = ((u64)b << 32) | (unsigned)~(n0 + 1); }
            b = __float_as_uint(v.z);
            if ((int)(b >> 16) >= T) { int p = atomicAdd(&sh_count, 1); if (p < CAND_CAP) keys[p] = ((u64)b << 32) | (unsigned)~(n0 + 2); }
            b = __float_as_uint(v.w);
            if ((int)(b >> 16) >= T) { int p = atomicAdd(&sh_count, 1); if (p < CAND_CAP) keys[p] = ((u64)b << 32) | (unsigned)~(n0 + 3); }
        }
    }
    __syncthreads();

    int count = sh_count;
    if (count > CAND_CAP) count = CAND_CAP;
    int M = 64;
    while (M < count) M <<= 1;
    for (int i = t; i < M; i += 1024)
        if (i >= count) keys[i] = 0ULL;
    __syncthreads();

    // (c) bitonic sort, descending
    for (int k = 2; k <= M; k <<= 1) {
        for (int j = k >> 1; j > 0; j >>= 1) {
            for (int i = t; i < M; i += 1024) {
                const int ixj = i ^ j;
                if (ixj > i) {
                    const u64 a = keys[i], b = keys[ixj];
                    const bool desc = (i & k) == 0;
                    if (desc ? (a < b) : (a > b)) { keys[i] = b; keys[ixj] = a; }
                }
            }
            __syncthreads();
        }
    }
    if (t < 64) idxs[t] = (int)~(unsigned)(keys[t] & 0xFFFFFFFFu);
    __syncthreads();

    // (d) gather: out[b, k, c] = src[b, c, idx[k]]
    for (int e = t; e < 3072; e += 1024) {
        const int b  = e / 384;
        const int r  = e % 384;
        const int kk = r / 6;
        const int c  = r % 6;
        out[e] = src[(b * 6 + c) * N_PTS + idxs[kk]];
    }
}

extern "C" void kernel_launch(void* const* d_in, const int* in_sizes, int n_in,
                              void* d_out, int out_size, void* d_ws, size_t ws_size,
                              hipStream_t stream)
{
    const float* src = (const float*)d_in[0];
    const float* W1 = (const float*)d_in[2];
    const float* b1 = (const float*)d_in[3];
    const float* W2 = (const float*)d_in[4];
    const float* b2 = (const float*)d_in[5];
    const float* Wa = (const float*)d_in[6];
    const float* ba = (const float*)d_in[7];
    const float* Wb = (const float*)d_in[8];
    const float* bb = (const float*)d_in[9];
    const float* Wc = (const float*)d_in[10];
    const float* bc = (const float*)d_in[11];

    char* ws = (char*)d_ws;
    float*    scores = (float*)ws;                   // 256 KB
    unsigned* hist   = (unsigned*)(ws + 256 * 1024); // 128 KB
    float*    out    = (float*)d_out;

    hipMemsetAsync(hist, 0, NBINS * sizeof(unsigned), stream);
    score_kernel<<<256, 256, 0, stream>>>(src, W1, b1, W2, b2, Wa, ba,
                                          Wb, bb, Wc, bc, scores, hist);
    select_kernel<<<1, 1024, 0, stream>>>(hist, scores, src, out);
}

// Round 4
// 212.144 us; speedup vs baseline: 1.1089x; 1.1089x over previous
//
#include <hip/hip_runtime.h>
#include <stdint.h>

#define N_PTS 65536
#define NBINS 32768      // positive f32 -> bits>>16 in [0, 32768)
#define CAND_CAP 4096
typedef unsigned long long u64;

// ws layout
//   [0    , 256K)      scores  f32[65536]
//   [256K , 384K)      hist    u32[32768]
//   [384K , 384K+64)   meta    i32  {0: cand_count}
//   [384K+64, +32K)    cand    u64[4096]

// ---------------------------------------------------------------------------
// K1: MLP score (batch 0), 4 threads per point (sub = t&3).
//   - sub-thread computes layer-2 neurons j = 4*jj+sub (16 of 64) and the
//     partial layer-3 contribution of those neurons to all 16 h3 outputs
//   - __shfl_xor(1)/(2) butterfly sums partials across the 4 sub-lanes
//   - layers 4/5 + softplus redundant on all 4 lanes; sub==0 stores + hist
// Weights in LDS, padded strides (8/36/20) -> aligned ds_read_b128,
// distinct banks across sub-lanes, broadcast across the 16 point-groups.
// ---------------------------------------------------------------------------
__global__ __launch_bounds__(256, 4) void score_kernel(
    const float* __restrict__ src,
    const float* __restrict__ W1, const float* __restrict__ b1,
    const float* __restrict__ W2, const float* __restrict__ b2,
    const float* __restrict__ Wa, const float* __restrict__ ba,
    const float* __restrict__ Wb, const float* __restrict__ bb,
    const float* __restrict__ Wc, const float* __restrict__ bc,
    float* __restrict__ scores, unsigned* __restrict__ hist)
{
    __shared__ float sW1[32 * 8];    // [32][8], cols 6..7 unused
    __shared__ float sW2[64 * 36];   // [64][36], cols 32..35 unused
    __shared__ float sWaT[64 * 20];  // [j][q] transposed, cols 16..19 unused
    __shared__ float sb1[32], sb2[64], sba[16], sWb[128], sbb[8], sWc[8], sbc1[1];
    const int t = threadIdx.x;

    for (int i = t; i < 32 * 8; i += 256) {
        const int j = i >> 3, c = i & 7;
        sW1[i] = (c < 6) ? W1[j * 6 + c] : 0.f;
    }
    for (int i = t; i < 64 * 36; i += 256) {
        const int j = i / 36, c = i % 36;
        sW2[i] = (c < 32) ? W2[j * 32 + c] : 0.f;
    }
    for (int i = t; i < 64 * 20; i += 256) {
        const int j = i / 20, q = i % 20;
        sWaT[i] = (q < 16) ? Wa[q * 64 + j] : 0.f;
    }
    if (t < 64)  sb2[t] = b2[t];
    if (t < 32)  sb1[t] = b1[t];
    if (t < 16)  sba[t] = ba[t];
    if (t < 128) sWb[t] = Wb[t];
    if (t < 8)   { sbb[t] = bb[t]; sWc[t] = Wc[t]; }
    if (t == 0)  sbc1[0] = bc[0];
    __syncthreads();

    const int sub = t & 3;
    const int p   = blockIdx.x * 64 + (t >> 2);

    float x[6];
    #pragma unroll
    for (int c = 0; c < 6; c++) x[c] = src[c * N_PTS + p];   // batch 0

    // layer 1: 6 -> 32 (redundant on all 4 sub-lanes; wave-uniform LDS reads)
    float h1[32];
    #pragma unroll
    for (int j = 0; j < 32; j++) {
        const float4 wA = *(const float4*)&sW1[j * 8];
        const float4 wB = *(const float4*)&sW1[j * 8 + 4];
        float a = sb1[j];
        a = fmaf(wA.x, x[0], a); a = fmaf(wA.y, x[1], a);
        a = fmaf(wA.z, x[2], a); a = fmaf(wA.w, x[3], a);
        a = fmaf(wB.x, x[4], a); a = fmaf(wB.y, x[5], a);
        h1[j] = fmaxf(a, 0.f);
    }

    // layers 2+3 fused over my 16 neurons (j = 4*jj + sub)
    float acc[16];
    #pragma unroll
    for (int q = 0; q < 16; q++) acc[q] = 0.f;

    #pragma unroll
    for (int jj = 0; jj < 16; jj++) {
        const int j = 4 * jj + sub;
        const float4* r2 = (const float4*)&sW2[j * 36];
        float a0 = 0.f, a1 = 0.f, a2 = 0.f, a3 = 0.f;
        #pragma unroll
        for (int i4 = 0; i4 < 8; i4++) {
            const float4 w = r2[i4];
            a0 = fmaf(w.x, h1[4 * i4 + 0], a0);
            a1 = fmaf(w.y, h1[4 * i4 + 1], a1);
            a2 = fmaf(w.z, h1[4 * i4 + 2], a2);
            a3 = fmaf(w.w, h1[4 * i4 + 3], a3);
        }
        const float val = fmaxf((a0 + a1) + (a2 + a3) + sb2[j], 0.f);
        const float4* rw = (const float4*)&sWaT[j * 20];
        #pragma unroll
        for (int q4 = 0; q4 < 4; q4++) {
            const float4 w = rw[q4];
            acc[4 * q4 + 0] = fmaf(w.x, val, acc[4 * q4 + 0]);
            acc[4 * q4 + 1] = fmaf(w.y, val, acc[4 * q4 + 1]);
            acc[4 * q4 + 2] = fmaf(w.z, val, acc[4 * q4 + 2]);
            acc[4 * q4 + 3] = fmaf(w.w, val, acc[4 * q4 + 3]);
        }
    }

    // butterfly-reduce partials across the 4 sub-lanes, then relu
    float h3[16];
    #pragma unroll
    for (int q = 0; q < 16; q++) {
        float pq = acc[q];
        pq += __shfl_xor(pq, 1);
        pq += __shfl_xor(pq, 2);
        h3[q] = fmaxf(pq + sba[q], 0.f);
    }

    // layers 4+5: 16 -> 8 -> 1 (redundant on all sub-lanes)
    float z = sbc1[0];
    #pragma unroll
    for (int j = 0; j < 8; j++) {
        float s0 = sbb[j], s1 = 0.f;
        #pragma unroll
        for (int q = 0; q < 16; q += 2) {
            s0 = fmaf(sWb[j * 16 + q + 0], h3[q + 0], s0);
            s1 = fmaf(sWb[j * 16 + q + 1], h3[q + 1], s1);
        }
        z = fmaf(sWc[j], fmaxf(s0 + s1, 0.f), z);
    }

    const float sp = fmaxf(z, 0.f) + log1pf(expf(-fabsf(z)));
    if (sub == 0) {
        scores[p] = sp;
        atomicAdd(&hist[__float_as_uint(sp) >> 16], 1u);
    }
}

// ---------------------------------------------------------------------------
// K2: compact with inline threshold scan. 64 blocks x 1024 threads.
// Each block redundantly suffix-scans the histogram (cheap, parallel),
// finds T = max bin with suffix >= 64, then compacts its 1024-score slice
// into the global candidate buffer via one atomic counter.
// Key = (score_bits << 32) | ~idx  -> value desc, lower idx first on ties.
// ---------------------------------------------------------------------------
__global__ __launch_bounds__(1024) void compact_kernel(
    const unsigned* __restrict__ hist, const float* __restrict__ scores,
    int* __restrict__ meta, u64* __restrict__ cand)
{
    __shared__ unsigned chunk[1024];
    __shared__ int sh_T;
    const int t = threadIdx.x;

    unsigned ssum = 0;
    const uint4* h4 = (const uint4*)(hist + t * 32);
    #pragma unroll
    for (int i = 0; i < 8; i++) {
        const uint4 v = h4[i];
        ssum += v.x + v.y + v.z + v.w;
    }
    chunk[t] = ssum;
    __syncthreads();
    for (int d = 1; d < 1024; d <<= 1) {
        const unsigned v = (t + d < 1024) ? chunk[t + d] : 0u;
        __syncthreads();
        chunk[t] += v;
        __syncthreads();
    }
    {
        const unsigned here = chunk[t];
        const unsigned nxt = (t + 1 < 1024) ? chunk[t + 1] : 0u;
        if (here >= 64u && nxt < 64u) {
            unsigned c = nxt;
            int T = t * 32;
            for (int b = t * 32 + 31; b >= t * 32; b--) {
                c += hist[b];
                if (c >= 64u) { T = b; break; }
            }
            sh_T = T;
        }
    }
    __syncthreads();
    const int T = sh_T;

    const int n = blockIdx.x * 1024 + t;
    const unsigned vb = __float_as_uint(scores[n]);
    if ((int)(vb >> 16) >= T) {
        const int pos = atomicAdd(&meta[0], 1);
        if (pos < CAND_CAP)
            cand[pos] = ((u64)vb << 32) | (unsigned)~n;
    }
}

// ---------------------------------------------------------------------------
// K3: rank-select (O(count^2), one barrier) + gather. 1 block x 1024.
// Keys are unique (idx field) -> ranks are a permutation; rank<64 wins.
// ---------------------------------------------------------------------------
__global__ __launch_bounds__(1024) void final_kernel(
    const int* __restrict__ meta, const u64* __restrict__ cand,
    const float* __restrict__ src, float* __restrict__ out)
{
    __shared__ u64 keys[CAND_CAP];
    __shared__ int idxs[64];
    const int t = threadIdx.x;

    int count = meta[0];
    if (count > CAND_CAP) count = CAND_CAP;

    for (int i = t; i < count; i += 1024) keys[i] = cand[i];
    __syncthreads();

    for (int i = t; i < count; i += 1024) {
        const u64 me = keys[i];
        int r = 0;
        for (int j = 0; j < count; j++) r += (keys[j] > me);
        if (r < 64) idxs[r] = (int)~(unsigned)(me & 0xFFFFFFFFu);
    }
    __syncthreads();

    // out[b, k, c] = src[b, c, idx[k]]  -> flat e = b*384 + k*6 + c
    for (int e = t; e < 3072; e += 1024) {
        const int b  = e / 384;
        const int rr = e % 384;
        const int kk = rr / 6;
        const int c  = rr % 6;
        out[e] = src[(b * 6 + c) * N_PTS + idxs[kk]];
    }
}

extern "C" void kernel_launch(void* const* d_in, const int* in_sizes, int n_in,
                              void* d_out, int out_size, void* d_ws, size_t ws_size,
                              hipStream_t stream)
{
    const float* src = (const float*)d_in[0];
    const float* W1 = (const float*)d_in[2];
    const float* b1 = (const float*)d_in[3];
    const float* W2 = (const float*)d_in[4];
    const float* b2 = (const float*)d_in[5];
    const float* Wa = (const float*)d_in[6];
    const float* ba = (const float*)d_in[7];
    const float* Wb = (const float*)d_in[8];
    const float* bb = (const float*)d_in[9];
    const float* Wc = (const float*)d_in[10];
    const float* bc = (const float*)d_in[11];

    char* ws = (char*)d_ws;
    float*    scores = (float*)ws;                          // 256 KB
    unsigned* hist   = (unsigned*)(ws + 256 * 1024);        // 128 KB
    int*      meta   = (int*)(ws + 384 * 1024);             // 64 B
    u64*      cand   = (u64*)(ws + 384 * 1024 + 64);        // 32 KB
    float*    out    = (float*)d_out;

    // zero hist + meta in one memset
    hipMemsetAsync(hist, 0, NBINS * sizeof(unsigned) + 64, stream);
    score_kernel<<<1024, 256, 0, stream>>>(src, W1, b1, W2, b2, Wa, ba,
                                           Wb, bb, Wc, bc, scores, hist);
    compact_kernel<<<64, 1024, 0, stream>>>(hist, scores, meta, cand);
    final_kernel<<<1, 1024, 0, stream>>>(meta, cand, src, out);
}

// Round 5
// 201.742 us; speedup vs baseline: 1.1661x; 1.0516x over previous
//
#include <hip/hip_runtime.h>
#include <stdint.h>

#define N_PTS 65536
#define NBINS 32768      // positive f32 -> bits>>16 in [0, 32768)
#define CAND_CAP 4096
typedef unsigned long long u64;

// ws layout
//   [0    , 256K)      scores  f32[65536]
//   [256K , 384K)      hist    u32[32768]
//   [384K , 384K+64)   meta    i32 {0: cand_count}
//   [384K+64, +32K)    cand    u64[4096]

// ---------------------------------------------------------------------------
// K1: MLP score (batch 0), ONE point per thread, 256 blocks x 256 threads
// (1 block/CU). All weight reads are wave-uniform aligned ds_read_b128
// (same-address broadcast = conflict-free). Wa is transposed at staging so
// layer 3 is 4x b128 per neuron. 4-way split accumulators give ILP; j-loop
// unrolled 4x for a load-prefetch window while staying I$-resident.
// ---------------------------------------------------------------------------
__global__ __launch_bounds__(256, 1) void score_kernel(
    const float* __restrict__ src,
    const float* __restrict__ W1, const float* __restrict__ b1,
    const float* __restrict__ W2, const float* __restrict__ b2,
    const float* __restrict__ Wa, const float* __restrict__ ba,
    const float* __restrict__ Wb, const float* __restrict__ bb,
    const float* __restrict__ Wc, const float* __restrict__ bc,
    float* __restrict__ scores, unsigned* __restrict__ hist)
{
    __shared__ __align__(16) float sW1[32 * 8];    // [j][c], cols 6..7 = 0
    __shared__ __align__(16) float sW2[64 * 32];   // [j][i], b128-aligned rows
    __shared__ __align__(16) float sWaT[64 * 16];  // [j][q] transposed
    __shared__ __align__(16) float sWb[8 * 16];    // [j][q]
    __shared__ float sb1[32], sb2[64], sba[16], sbb[8], sWc[8], sbc1[1];
    const int t = threadIdx.x;

    {
        const int j = t >> 3, c = t & 7;
        sW1[t] = (c < 6) ? W1[j * 6 + c] : 0.f;
    }
    for (int i = t; i < 2048; i += 256) sW2[i] = W2[i];
    for (int i = t; i < 1024; i += 256) {
        const int j = i >> 4, q = i & 15;
        sWaT[i] = Wa[q * 64 + j];
    }
    if (t < 128) sWb[t] = Wb[t];
    if (t < 64)  sb2[t] = b2[t];
    if (t < 32)  sb1[t] = b1[t];
    if (t < 16)  sba[t] = ba[t];
    if (t < 8)   { sbb[t] = bb[t]; sWc[t] = Wc[t]; }
    if (t == 0)  sbc1[0] = bc[0];
    __syncthreads();

    const int p = blockIdx.x * 256 + t;

    float x0 = src[0 * N_PTS + p], x1 = src[1 * N_PTS + p];
    float x2 = src[2 * N_PTS + p], x3 = src[3 * N_PTS + p];
    float x4 = src[4 * N_PTS + p], x5 = src[5 * N_PTS + p];

    // layer 1: 6 -> 32
    float h1[32];
    #pragma unroll
    for (int j = 0; j < 32; j++) {
        const float4 wA = *(const float4*)&sW1[j * 8];
        const float4 wB = *(const float4*)&sW1[j * 8 + 4];
        float a = sb1[j];
        a = fmaf(wA.x, x0, a); a = fmaf(wA.y, x1, a);
        a = fmaf(wA.z, x2, a); a = fmaf(wA.w, x3, a);
        a = fmaf(wB.x, x4, a); a = fmaf(wB.y, x5, a);
        h1[j] = fmaxf(a, 0.f);
    }

    // layers 2+3 fused: 32 -> 64 -> 16
    float h3[16];
    #pragma unroll
    for (int q = 0; q < 16; q++) h3[q] = sba[q];

    #pragma unroll 4
    for (int j = 0; j < 64; j++) {
        const float4* w2r = (const float4*)&sW2[j * 32];
        float a0 = 0.f, a1 = 0.f, a2 = 0.f, a3 = 0.f;
        #pragma unroll
        for (int i4 = 0; i4 < 8; i4++) {
            const float4 w = w2r[i4];
            a0 = fmaf(w.x, h1[4 * i4 + 0], a0);
            a1 = fmaf(w.y, h1[4 * i4 + 1], a1);
            a2 = fmaf(w.z, h1[4 * i4 + 2], a2);
            a3 = fmaf(w.w, h1[4 * i4 + 3], a3);
        }
        const float v = fmaxf((a0 + a1) + (a2 + a3) + sb2[j], 0.f);
        const float4* war = (const float4*)&sWaT[j * 16];
        #pragma unroll
        for (int q4 = 0; q4 < 4; q4++) {
            const float4 w = war[q4];
            h3[4 * q4 + 0] = fmaf(w.x, v, h3[4 * q4 + 0]);
            h3[4 * q4 + 1] = fmaf(w.y, v, h3[4 * q4 + 1]);
            h3[4 * q4 + 2] = fmaf(w.z, v, h3[4 * q4 + 2]);
            h3[4 * q4 + 3] = fmaf(w.w, v, h3[4 * q4 + 3]);
        }
    }
    #pragma unroll
    for (int q = 0; q < 16; q++) h3[q] = fmaxf(h3[q], 0.f);

    // layers 4+5: 16 -> 8 -> 1
    float z = sbc1[0];
    #pragma unroll
    for (int j = 0; j < 8; j++) {
        const float4* wbr = (const float4*)&sWb[j * 16];
        const float4 wA = wbr[0], wB = wbr[1], wC = wbr[2], wD = wbr[3];
        float s0 = sbb[j], s1 = 0.f, s2 = 0.f, s3 = 0.f;
        s0 = fmaf(wA.x, h3[0],  s0); s1 = fmaf(wA.y, h3[1],  s1);
        s2 = fmaf(wA.z, h3[2],  s2); s3 = fmaf(wA.w, h3[3],  s3);
        s0 = fmaf(wB.x, h3[4],  s0); s1 = fmaf(wB.y, h3[5],  s1);
        s2 = fmaf(wB.z, h3[6],  s2); s3 = fmaf(wB.w, h3[7],  s3);
        s0 = fmaf(wC.x, h3[8],  s0); s1 = fmaf(wC.y, h3[9],  s1);
        s2 = fmaf(wC.z, h3[10], s2); s3 = fmaf(wC.w, h3[11], s3);
        s0 = fmaf(wD.x, h3[12], s0); s1 = fmaf(wD.y, h3[13], s1);
        s2 = fmaf(wD.z, h3[14], s2); s3 = fmaf(wD.w, h3[15], s3);
        z = fmaf(sWc[j], fmaxf((s0 + s1) + (s2 + s3), 0.f), z);
    }

    const float sp = fmaxf(z, 0.f) + log1pf(expf(-fabsf(z)));
    scores[p] = sp;
    atomicAdd(&hist[__float_as_uint(sp) >> 16], 1u);
}

// ---------------------------------------------------------------------------
// K2: threshold scan + compact. 64 blocks x 256 threads.
// Each block redundantly finds T = max bin with suffix >= 64 (8-step scan
// over 256 chunk-sums, then 7-step refine over the 128 bins of the critical
// chunk), then compacts its 1024-score slice (float4 loads) into cand.
// Key = (score_bits << 32) | ~idx -> value desc, lower idx first on ties.
// ---------------------------------------------------------------------------
__global__ __launch_bounds__(256) void compact_kernel(
    const unsigned* __restrict__ hist, const float* __restrict__ scores,
    int* __restrict__ meta, u64* __restrict__ cand)
{
    __shared__ unsigned csum[256];
    __shared__ unsigned bsum[128];
    __shared__ int sh_c, sh_T;
    __shared__ unsigned sh_tail;
    const int t = threadIdx.x;

    // chunk sums: thread t sums bins [t*128, t*128+128)
    {
        unsigned s = 0;
        const uint4* h4 = (const uint4*)(hist + t * 128);
        #pragma unroll
        for (int i = 0; i < 32; i++) {
            const uint4 v = h4[i];
            s += v.x + v.y + v.z + v.w;
        }
        csum[t] = s;
    }
    __syncthreads();
    for (int d = 1; d < 256; d <<= 1) {
        const unsigned v = (t + d < 256) ? csum[t + d] : 0u;
        __syncthreads();
        csum[t] += v;
        __syncthreads();
    }
    {
        const unsigned here = csum[t];
        const unsigned nxt = (t + 1 < 256) ? csum[t + 1] : 0u;
        if (here >= 64u && nxt < 64u) { sh_c = t; sh_tail = nxt; }
    }
    __syncthreads();
    const int cstar = sh_c;
    const unsigned tail = sh_tail;

    if (t < 128) bsum[t] = hist[cstar * 128 + t];
    __syncthreads();
    for (int d = 1; d < 128; d <<= 1) {
        unsigned v = 0u;
        if (t < 128 && t + d < 128) v = bsum[t + d];
        __syncthreads();
        if (t < 128) bsum[t] += v;
        __syncthreads();
    }
    if (t < 128) {
        const unsigned here = bsum[t] + tail;
        const unsigned nxt = (t + 1 < 128) ? bsum[t + 1] + tail : tail;
        if (here >= 64u && nxt < 64u) sh_T = cstar * 128 + t;
    }
    __syncthreads();
    const int T = sh_T;

    // compact this block's 1024-point slice (4 points/thread, float4)
    const float4* s4 = (const float4*)scores;
    const int i = blockIdx.x * 256 + t;
    const float4 v = s4[i];
    const int n0 = 4 * i;
    unsigned b;
    b = __float_as_uint(v.x);
    if ((int)(b >> 16) >= T) { int p = atomicAdd(&meta[0], 1); if (p < CAND_CAP) cand[p] = ((u64)b << 32) | (unsigned)~(n0 + 0); }
    b = __float_as_uint(v.y);
    if ((int)(b >> 16) >= T) { int p = atomicAdd(&meta[0], 1); if (p < CAND_CAP) cand[p] = ((u64)b << 32) | (unsigned)~(n0 + 1); }
    b = __float_as_uint(v.z);
    if ((int)(b >> 16) >= T) { int p = atomicAdd(&meta[0], 1); if (p < CAND_CAP) cand[p] = ((u64)b << 32) | (unsigned)~(n0 + 2); }
    b = __float_as_uint(v.w);
    if ((int)(b >> 16) >= T) { int p = atomicAdd(&meta[0], 1); if (p < CAND_CAP) cand[p] = ((u64)b << 32) | (unsigned)~(n0 + 3); }
}

// ---------------------------------------------------------------------------
// K3: rank-select (O(count^2), count ~ 100) + gather. 1 block x 256.
// Keys unique (idx field) -> ranks form a permutation; rank < 64 wins.
// ---------------------------------------------------------------------------
__global__ __launch_bounds__(256) void final_kernel(
    const int* __restrict__ meta, const u64* __restrict__ cand,
    const float* __restrict__ src, float* __restrict__ out)
{
    __shared__ u64 keys[CAND_CAP];
    __shared__ int idxs[64];
    const int t = threadIdx.x;

    int count = meta[0];
    if (count > CAND_CAP) count = CAND_CAP;

    for (int i = t; i < count; i += 256) keys[i] = cand[i];
    __syncthreads();

    for (int i = t; i < count; i += 256) {
        const u64 me = keys[i];
        int r = 0;
        for (int j = 0; j < count; j++) r += (keys[j] > me);
        if (r < 64) idxs[r] = (int)~(unsigned)(me & 0xFFFFFFFFu);
    }
    __syncthreads();

    // out[b, k, c] = src[b, c, idx[k]]  -> flat e = b*384 + k*6 + c
    for (int e = t; e < 3072; e += 256) {
        const int b  = e / 384;
        const int rr = e % 384;
        const int kk = rr / 6;
        const int c  = rr % 6;
        out[e] = src[(b * 6 + c) * N_PTS + idxs[kk]];
    }
}

extern "C" void kernel_launch(void* const* d_in, const int* in_sizes, int n_in,
                              void* d_out, int out_size, void* d_ws, size_t ws_size,
                              hipStream_t stream)
{
    const float* src = (const float*)d_in[0];
    const float* W1 = (const float*)d_in[2];
    const float* b1 = (const float*)d_in[3];
    const float* W2 = (const float*)d_in[4];
    const float* b2 = (const float*)d_in[5];
    const float* Wa = (const float*)d_in[6];
    const float* ba = (const float*)d_in[7];
    const float* Wb = (const float*)d_in[8];
    const float* bb = (const float*)d_in[9];
    const float* Wc = (const float*)d_in[10];
    const float* bc = (const float*)d_in[11];

    char* ws = (char*)d_ws;
    float*    scores = (float*)ws;                          // 256 KB
    unsigned* hist   = (unsigned*)(ws + 256 * 1024);        // 128 KB
    int*      meta   = (int*)(ws + 384 * 1024);             // 64 B
    u64*      cand   = (u64*)(ws + 384 * 1024 + 64);        // 32 KB
    float*    out    = (float*)d_out;

    hipMemsetAsync(hist, 0, NBINS * sizeof(unsigned) + 64, stream);
    score_kernel<<<256, 256, 0, stream>>>(src, W1, b1, W2, b2, Wa, ba,
                                          Wb, bb, Wc, bc, scores, hist);
    compact_kernel<<<64, 256, 0, stream>>>(hist, scores, meta, cand);
    final_kernel<<<1, 256, 0, stream>>>(meta, cand, src, out);
}